// Round 8
// baseline (55.690 us; speedup 1.0000x reference)
//
#include <hip/hip_runtime.h>

#define IMGD 28
#define OUTD 26
#define NCLS 10
#define NIMG 64
#define U3 21                        // float4 units per image per 3-row band (odd -> bank-clean)
#define U1 7                         // tail band: 1 row
#define BW3 (NIMG * U3 * 4)          // 5376 floats = 21504 B per buffer
#define THREADS 1024
#define LDSTRIDE 11

typedef float v2f __attribute__((ext_vector_type(2)));

__device__ __forceinline__ void gload_lds16(const float* gp, float* lp) {
    __builtin_amdgcn_global_load_lds(
        (const __attribute__((address_space(1))) void*)gp,
        (__attribute__((address_space(3))) void*)lp, 16, 0, 0);
}

// Stage one disjoint band (UNITS float4-units per image, input rows r0..) of
// 64 images. LDS [img][unit] linear, stride UNITS odd -> ds_read_b128 at
// (UNITS*lane + u) % 8 hits all 8 bank-quads: conflict-free. Global source:
// contiguous 336B (or 112B) block per image -> coalesced.
template<int UNITS>
__device__ __forceinline__ void stage_band(const float* __restrict__ x,
                                           int img_base, int B, int r0,
                                           float* buf, int wv, int lane)
{
#pragma unroll
    for (int it = 0; it * 16 < UNITS; ++it) {
        const int fw = it * 16 + wv;             // wave-uniform chunk id
        if (fw < UNITS) {
            const int f = fw * 64 + lane;        // flat unit index
            const int g = f / UNITS;             // image 0..63 (const-div)
            const int s = f - g * UNITS;         // unit within band
            int gi = img_base + g; if (gi >= B) gi = B - 1;
            const float* gp = x + (size_t)gi * (IMGD * IMGD) + r0 * IMGD + s * 4;
            gload_lds16(gp, buf + fw * 256);     // uniform base + lane*16B
        }
    }
}

// read NU float4 units (band row br, unit col u0) of image `lane`
template<int NU, int STRIDE>
__device__ __forceinline__ void read_row(const float* buf, int lane, int br, int u0,
                                         float* dst)
{
    const float4* b4 = (const float4*)buf;
#pragma unroll
    for (int u = 0; u < NU; ++u) {
        float4 a = b4[lane * STRIDE + br * 7 + u0 + u];
        dst[4*u+0] = a.x; dst[4*u+1] = a.y; dst[4*u+2] = a.z; dst[4*u+3] = a.w;
    }
}

// one width-2 output pair: conv3x3 (tree) + relu + rank-1 GEMM, W wave-uniform
template<int OFF, int NR>
__device__ __forceinline__ void conv_row(const float (&X)[NR], const float (&Y)[NR],
                                         const float (&Z)[NR], const float (&kk)[9],
                                         const float* __restrict__ wr, v2f* acc)
{
#pragma unroll
    for (int c = 0; c < 2; ++c) {
        float p0 = fmaf(X[OFF+c], kk[0], X[OFF+c+1] * kk[1]);
        p0 = fmaf(X[OFF+c+2], kk[2], p0);
        float p1 = fmaf(Y[OFF+c], kk[3], Y[OFF+c+1] * kk[4]);
        p1 = fmaf(Y[OFF+c+2], kk[5], p1);
        float p2 = fmaf(Z[OFF+c], kk[6], Z[OFF+c+1] * kk[7]);
        p2 = fmaf(Z[OFF+c+2], kk[8], p2);
        float v = fmaxf((p0 + p1) + p2, 0.0f);
        const float* w = wr + c * NCLS;          // wave-uniform -> s_load
#pragma unroll
        for (int p = 0; p < 5; ++p) {
            v2f wv2 = *(const v2f*)(w + 2 * p);
            v2f vv; vv[0] = v; vv[1] = v;
            acc[p] += vv * wv2;                  // v_pk_fma_f32
        }
    }
}

// 3-buffer rotation, ONE barrier per phase, depth-2 prefetch.
// Phase k (k=0..8, band rows 3k..3k+2):
//   vmcnt(band k+1's share) ; barrier ; stage band k+2 -> buf[(k+2)%3]
//   (overwrites band k-1: its reads finished in phase k-1, fenced by this
//   barrier) ; compute outputs 3k-2, 3k-1, 3k via 2-row register halo.
// Phase 9: tail row 27 -> output 25.
// NU=0 instantiation: idle wave (stage+barrier only). Identical barrier
// structure across all instantiations.
template<int NU, int OFF>
__device__ __forceinline__ void run_all(
    const float* __restrict__ x, int img_base, int B,
    float* lds0, int wv, int lane, int u0, int c0,
    const float* __restrict__ cw, const float* __restrict__ Wp, v2f* acc)
{
    constexpr int NR = 4 * (NU ? NU : 1);
    float kk[9];
#pragma unroll
    for (int i = 0; i < 9; ++i) kk[i] = cw[i];   // uniform -> SGPRs

    float S0[NR], S1[NR];                        // 2-row register halo

    stage_band<U3>(x, img_base, B, 0, lds0,       wv, lane);
    stage_band<U3>(x, img_base, B, 3, lds0 + BW3, wv, lane);

#pragma unroll
    for (int k = 0; k < 9; ++k) {
        // wait band k; leave band k+1 (and later) in flight
        if (k < 8) {                             // band k+1 = 21-unit band
            if (wv < 5) asm volatile("s_waitcnt vmcnt(2)" ::: "memory");
            else        asm volatile("s_waitcnt vmcnt(1)" ::: "memory");
        } else {                                 // band 9 = tail (7 units)
            if (wv < 7) asm volatile("s_waitcnt vmcnt(1)" ::: "memory");
            else        asm volatile("s_waitcnt vmcnt(0)" ::: "memory");
        }
        __builtin_amdgcn_s_barrier();            // band k landed for ALL waves

        // stage next-next band before compute: queue never drains
        if (k < 7)
            stage_band<U3>(x, img_base, B, 3 * (k + 2),
                           lds0 + ((k + 2) % 3) * BW3, wv, lane);
        else if (k == 7)
            stage_band<U1>(x, img_base, B, 27, lds0, wv, lane);  // 9%3 == 0

        const float* buf = lds0 + (k % 3) * BW3;

        if (NU > 0) {
            float Ta[NR], Tb[NR], Tc[NR];
            read_row<(NU?NU:1), U3>(buf, lane, 0, u0, Ta);
            if (k > 0)
                conv_row<OFF>(S0, S1, Ta, kk,
                              Wp + ((size_t)(3*k-2) * OUTD + c0) * NCLS, acc);
            read_row<(NU?NU:1), U3>(buf, lane, 1, u0, Tb);
            if (k > 0)
                conv_row<OFF>(S1, Ta, Tb, kk,
                              Wp + ((size_t)(3*k-1) * OUTD + c0) * NCLS, acc);
            read_row<(NU?NU:1), U3>(buf, lane, 2, u0, Tc);
            conv_row<OFF>(Ta, Tb, Tc, kk,
                          Wp + ((size_t)(3*k) * OUTD + c0) * NCLS, acc);
#pragma unroll
            for (int i = 0; i < NR; ++i) { S0[i] = Tb[i]; S1[i] = Tc[i]; }
        }
    }

    // tail phase: row 27 in buf0 -> output 25
    asm volatile("s_waitcnt vmcnt(0)" ::: "memory");
    __builtin_amdgcn_s_barrier();
    if (NU > 0) {
        float Ta[NR];
        read_row<(NU?NU:1), U1>(lds0, lane, 0, u0, Ta);
        conv_row<OFF>(S0, S1, Ta, kk,
                      Wp + ((size_t)25 * OUTD + c0) * NCLS, acc);
    }
}

__global__ __launch_bounds__(THREADS, 8) void fused_conv_relu_fc(
    const float* __restrict__ x,      // [B, 784]
    const float* __restrict__ cw,     // [9]
    const float* __restrict__ Wp,     // [676, 10]
    const float* __restrict__ bp,     // [10]
    float* __restrict__ out,          // [B, 10]
    int B)
{
    __shared__ float lds[3 * BW3];               // 64512 B -> 2 blocks/CU

    const int lane = threadIdx.x & 63;
    const int wv   = __builtin_amdgcn_readfirstlane((int)(threadIdx.x >> 6));
    const int img_base = blockIdx.x * NIMG;

    v2f acc[5];
#pragma unroll
    for (int p = 0; p < 5; ++p) { acc[p][0] = 0.0f; acc[p][1] = 0.0f; }

    // 13 active waves x width-2 col strips (c0 = 2*wv); 3 idle waves keep
    // staging/barrier duty. Even wv: aligned (NU1); odd wv: offset 2 (NU2).
    if (wv < 13) {
        if (wv & 1) run_all<2,2>(x, img_base, B, lds, wv, lane, (wv-1)/2, 2*wv, cw, Wp, acc);
        else        run_all<1,0>(x, img_base, B, lds, wv, lane, wv/2,     2*wv, cw, Wp, acc);
    } else        run_all<0,0>(x, img_base, B, lds, wv, lane, 0, 0, cw, Wp, acc);

    __syncthreads();                             // all band reads done before overlay

    // partials -> LDS overlay (stride 11: 2 lanes/bank -> free)
    float* part = lds;                           // 45056 B < 64512
    float* myp = &part[(wv * 64 + lane) * LDSTRIDE];
#pragma unroll
    for (int p = 0; p < 5; ++p) { myp[2*p] = acc[p][0]; myp[2*p+1] = acc[p][1]; }
    __syncthreads();

    // combine 16 partials (3 are zero) + bias; coalesced 640-float store
    const int o = threadIdx.x;
    if (o < NIMG * NCLS) {
        const int im = o / NCLS;
        const int c  = o - im * NCLS;
        float s = bp[c];
#pragma unroll
        for (int w2 = 0; w2 < 16; ++w2)
            s += part[(w2 * 64 + im) * LDSTRIDE + c];
        if (img_base + im < B)
            out[(size_t)(img_base + im) * NCLS + c] = s;
    }
}

extern "C" void kernel_launch(void* const* d_in, const int* in_sizes, int n_in,
                              void* d_out, int out_size, void* d_ws, size_t ws_size,
                              hipStream_t stream) {
    const float* x  = (const float*)d_in[0];
    const float* cw = (const float*)d_in[1];
    const float* Wp = (const float*)d_in[2];
    const float* bp = (const float*)d_in[3];
    float* out = (float*)d_out;

    const int B = in_sizes[0] / (IMGD * IMGD);   // 32768
    const int grid = (B + NIMG - 1) / NIMG;      // 512 blocks x 16 waves

    fused_conv_relu_fc<<<grid, THREADS, 0, stream>>>(x, cw, Wp, bp, out, B);
}